// Round 3
// baseline (651.856 us; speedup 1.0000x reference)
//
#include <hip/hip_runtime.h>
#include <hip/hip_bf16.h>
#include <stdint.h>

// Problem constants (fixed by setup_inputs)
#define M_TOTAL   65536     // B*N = 16*4096
#define K_ORIG    588       // D_in
#define K_PAD     608       // 19*32, zero-padded K
#define H_DIM     1152
#define P_DIM     4096
#define KT_STEPS  19        // K_PAD / 32

typedef short bf16x8 __attribute__((ext_vector_type(8)));
typedef float f32x4  __attribute__((ext_vector_type(4)));

__device__ __forceinline__ unsigned short f2bf(float f) {
  __hip_bfloat16 h = __float2bfloat16(f);
  return __builtin_bit_cast(unsigned short, h);
}

__device__ __forceinline__ void gload_lds16(const void* g, void* s) {
  __builtin_amdgcn_global_load_lds(
      (const __attribute__((address_space(1))) void*)g,
      (__attribute__((address_space(3))) void*)s, 16, 0, 0);
}

// ---- Prepass 1: patches = bf16(2*x - 1), padded [M][K_PAD] ----
// one thread per 4 consecutive k; K_PAD/4 = 152 groups per row.
__global__ void convert_patches(const float* __restrict__ px,
                                unsigned short* __restrict__ out) {
  const int64_t i = (int64_t)blockIdx.x * blockDim.x + threadIdx.x;
  const int g = (int)(i % 152);
  const int64_t m = i / 152;
  const int k0 = g * 4;
  ushort4 o;
  if (k0 < K_ORIG) {  // 588 % 4 == 0, so groups are fully in or fully out
    const float4 v = *(const float4*)(px + m * K_ORIG + k0);
    o.x = f2bf(2.f * v.x - 1.f);
    o.y = f2bf(2.f * v.y - 1.f);
    o.z = f2bf(2.f * v.z - 1.f);
    o.w = f2bf(2.f * v.w - 1.f);
  } else {
    o.x = 0; o.y = 0; o.z = 0; o.w = 0;
  }
  *(ushort4*)(out + m * K_PAD + k0) = o;
}

// ---- Prepass 2: Wt[h][k] = bf16(W[k][h]), padded [H][K_PAD] ----
__global__ void convert_w(const float* __restrict__ W,
                          unsigned short* __restrict__ Wt) {
  const int i = blockIdx.x * blockDim.x + threadIdx.x;
  const int k = i % K_PAD;
  const int h = i / K_PAD;
  Wt[i] = (k < K_ORIG) ? f2bf(W[(int64_t)k * H_DIM + h]) : (unsigned short)0;
}

// ---- GEMM: C[M][H] = A @ Wt^T + gathered pos-emb ----
// 128x128 tile, 4 waves (2x2 of 64x64), 16x16x32 bf16 MFMA, BK=32.
// global_load_lds width-16 staging with XOR-swizzled SOURCE addresses
// (linear LDS dest); frag ds_reads use the matching swizzle -> ~2-way
// bank aliasing (free, m136).
__global__ void __launch_bounds__(256) gemm_fused(
    const unsigned short* __restrict__ A,     // [M][K_PAD] bf16 bits
    const unsigned short* __restrict__ Bt,    // [H][K_PAD] bf16 bits
    const int* __restrict__ ids,              // [M][2] int32
    const unsigned char* __restrict__ padm,   // [M] (bytes; all-zero data)
    const float* __restrict__ ptab,           // [2][P][H] f32
    float* __restrict__ out) {                // [M][H] f32
  __shared__ __align__(16) unsigned short Ash[128 * 32];
  __shared__ __align__(16) unsigned short Bsh[128 * 32];
  __shared__ int p0s[128];
  __shared__ int p1s[128];
  __shared__ unsigned char mks[128];

  const int tid = threadIdx.x;
  const int w   = tid >> 6;
  const int l   = tid & 63;
  const int bm  = blockIdx.x / 9;   // 9 consecutive blocks share the A panel
  const int bn  = blockIdx.x % 9;
  const int wm  = w >> 1;
  const int wn  = w & 1;

  if (tid < 128) {
    const int gm = bm * 128 + tid;
    const int q0 = ids[2 * gm + 0];
    const int q1 = ids[2 * gm + 1];
    p0s[tid] = q0 < 0 ? 0 : q0;
    p1s[tid] = q1 < 0 ? 0 : q1;
    mks[tid] = padm[gm];
  }

  f32x4 acc[4][4];
#pragma unroll
  for (int i = 0; i < 4; ++i)
#pragma unroll
    for (int j = 0; j < 4; ++j) acc[i][j] = f32x4{0.f, 0.f, 0.f, 0.f};

  // Staging geometry: per gload_lds inst, lane l covers tile row r0+l/4,
  // 16B k-chunk (l%4). Source k-chunk is XOR-swizzled so that the linear
  // LDS write lands data where the swizzled frag-read expects it.
  const int srow = l >> 2;
  const int sk   = ((l & 3) ^ ((l >> 3) & 3)) * 8;  // swizzled k elem offset
  const int64_t abase = (int64_t)(bm * 128) * K_PAD;
  const int64_t bbase = (int64_t)(bn * 128) * K_PAD;

  // Frag-read LDS element offsets (swizzle: chunk = (l>>4) ^ ((row>>1)&3))
  int ra[4], rb[4];
#pragma unroll
  for (int mi = 0; mi < 4; ++mi) {
    const int rA = wm * 64 + mi * 16 + (l & 15);
    ra[mi] = rA * 32 + (((l >> 4) ^ ((rA >> 1) & 3)) * 8);
    const int rB = wn * 64 + mi * 16 + (l & 15);
    rb[mi] = rB * 32 + (((l >> 4) ^ ((rB >> 1) & 3)) * 8);
  }

  for (int kt = 0; kt < KT_STEPS; ++kt) {
    const int k0 = kt * 32;
#pragma unroll
    for (int i = 0; i < 2; ++i) {
      const int r0 = (w * 2 + i) * 16;  // 16-row chunk staged per inst
      gload_lds16(A + abase + (int64_t)(r0 + srow) * K_PAD + k0 + sk,
                  &Ash[r0 * 32]);
      gload_lds16(Bt + bbase + (int64_t)(r0 + srow) * K_PAD + k0 + sk,
                  &Bsh[r0 * 32]);
    }
    __syncthreads();

    bf16x8 av[4], bv[4];
#pragma unroll
    for (int mi = 0; mi < 4; ++mi) av[mi] = *(const bf16x8*)&Ash[ra[mi]];
#pragma unroll
    for (int ni = 0; ni < 4; ++ni) bv[ni] = *(const bf16x8*)&Bsh[rb[ni]];
#pragma unroll
    for (int mi = 0; mi < 4; ++mi)
#pragma unroll
      for (int ni = 0; ni < 4; ++ni)
        acc[mi][ni] = __builtin_amdgcn_mfma_f32_16x16x32_bf16(
            av[mi], bv[ni], acc[mi][ni], 0, 0, 0);
    __syncthreads();
  }

  // Epilogue: C/D layout col = lane&15, row = (lane>>4)*4 + reg (m89).
  const int c  = l & 15;
  const int rg = (l >> 4) * 4;
  const float* T0 = ptab;
  const float* T1 = ptab + (int64_t)P_DIM * H_DIM;
  const int hcol0 = bn * 128 + wn * 64;

#pragma unroll
  for (int mi = 0; mi < 4; ++mi) {
#pragma unroll
    for (int j = 0; j < 4; ++j) {
      const int r = wm * 64 + mi * 16 + rg + j;
      const int64_t gm = (int64_t)bm * 128 + r;
      const bool pad = mks[r] != 0;
      const float* t0 = T0 + (int64_t)p0s[r] * H_DIM;
      const float* t1 = T1 + (int64_t)p1s[r] * H_DIM;
      float* orow = out + gm * H_DIM;
#pragma unroll
      for (int ni = 0; ni < 4; ++ni) {
        const int gh = hcol0 + ni * 16 + c;
        const float pe = pad ? 0.f : (t0[gh] + t1[gh]);
        orow[gh] = acc[mi][ni][j] + pe;
      }
    }
  }
}

extern "C" void kernel_launch(void* const* d_in, const int* in_sizes, int n_in,
                              void* d_out, int out_size, void* d_ws,
                              size_t ws_size, hipStream_t stream) {
  const float* px            = (const float*)d_in[0];
  const int* ids             = (const int*)d_in[1];
  const unsigned char* padm  = (const unsigned char*)d_in[2];
  const float* W             = (const float*)d_in[3];
  const float* pt            = (const float*)d_in[4];
  float* out                 = (float*)d_out;

  unsigned short* Apad = (unsigned short*)d_ws;                   // 79.7 MB
  unsigned short* Wt   = Apad + (size_t)M_TOTAL * K_PAD;          // +1.4 MB

  // 65536*152/256 = 38912 blocks exactly
  convert_patches<<<38912, 256, 0, stream>>>(px, Apad);
  // 1152*608/256 = 2736 blocks exactly
  convert_w<<<2736, 256, 0, stream>>>(W, Wt);
  // (65536/128) * (1152/128) = 512*9 = 4608 blocks
  gemm_fused<<<4608, 256, 0, stream>>>(Apad, Wt, ids, padm, pt, out);
}

// Round 8
// 638.505 us; speedup vs baseline: 1.0209x; 1.0209x over previous
//
#include <hip/hip_runtime.h>
#include <hip/hip_bf16.h>
#include <stdint.h>

// Problem constants (fixed by setup_inputs)
#define M_TOTAL   65536     // B*N = 16*4096
#define K_ORIG    588       // D_in
#define K_PAD     608       // 19*32, zero-padded K (Wt only)
#define H_DIM     1152
#define P_DIM     4096
#define KT_STEPS  19        // ceil(588/32)

typedef short bf16x8 __attribute__((ext_vector_type(8)));
typedef float f32x4  __attribute__((ext_vector_type(4)));

__device__ __forceinline__ unsigned short f2bf(float f) {
  __hip_bfloat16 h = __float2bfloat16(f);
  return __builtin_bit_cast(unsigned short, h);
}

__device__ __forceinline__ void gload_lds16(const void* g, void* s) {
  __builtin_amdgcn_global_load_lds(
      (const __attribute__((address_space(1))) void*)g,
      (__attribute__((address_space(3))) void*)s, 16, 0, 0);
}

// ---- Prepass: Wt[h][k] = bf16(W[k][h]), padded [H][K_PAD], LDS-tiled ----
// 32x32 f32 tiles, both global sides coalesced. 2.7 MB read / 1.4 MB write.
__global__ void __launch_bounds__(256) convert_w(const float* __restrict__ W,
                                                 unsigned short* __restrict__ Wt) {
  __shared__ float tile[32][33];
  const int kt = blockIdx.x % 19;
  const int ht = blockIdx.x / 19;
  const int k0 = kt * 32, h0 = ht * 32;
  const int r = threadIdx.x >> 5;   // 0..7
  const int c = threadIdx.x & 31;   // 0..31
#pragma unroll
  for (int i = 0; i < 4; ++i) {
    const int k = k0 + r + i * 8;
    tile[r + i * 8][c] = (k < K_ORIG) ? W[(int64_t)k * H_DIM + h0 + c] : 0.f;
  }
  __syncthreads();
#pragma unroll
  for (int i = 0; i < 4; ++i) {
    const int h = h0 + r + i * 8;
    Wt[(int64_t)h * K_PAD + k0 + c] = f2bf(tile[c][r + i * 8]);
  }
}

// ---- Fused GEMM: C[M][H] = bf16(2*px-1) @ Wt^T + gathered pos-emb ----
// 128x128 tile, 4 waves (2x2 of 64x64), 16x16x32 bf16 MFMA, BK=32,
// double-buffered LDS, single barrier per K-step (2-phase pipeline):
//   issue B gload_lds(t+1) + A global loads(t+1)  -> overlap with
//   ds_read + 16 MFMA of step t -> cvt+ds_write A(t+1) -> barrier.
// A is reg-staged (conversion fused, tail zero-padded in regs).
// B staged via global_load_lds with pre-swizzled SOURCE (rule #21);
// A ds_writes use the same XOR swizzle -> conflict-free ds_read_b128.
__global__ void __launch_bounds__(256) gemm_fused(
    const float* __restrict__ px,             // [M][588] f32
    const unsigned short* __restrict__ Bt,    // [H][K_PAD] bf16 bits
    const int* __restrict__ ids,              // [M][2] int32
    const unsigned char* __restrict__ padm,   // [M]
    const float* __restrict__ ptab,           // [2][P][H] f32
    float* __restrict__ out) {                // [M][H] f32
  __shared__ __align__(16) unsigned short Ash[2][128 * 32];
  __shared__ __align__(16) unsigned short Bsh[2][128 * 32];
  __shared__ int p0s[128];
  __shared__ int p1s[128];
  __shared__ unsigned char mks[128];

  const int tid = threadIdx.x;
  const int w   = tid >> 6;
  const int l   = tid & 63;

  // Chunked XCD swizzle (4608 % 8 == 0 -> bijective): each XCD owns a
  // contiguous 576-block range = 64 A-panels x 9 bn -> A-panel L2 locality.
  const int bid = blockIdx.x;
  const int lin = (bid >> 3) + (bid & 7) * 576;
  const int bm  = lin / 9;
  const int bn  = lin % 9;
  const int wm  = w >> 1;
  const int wn  = w & 1;

  if (tid < 128) {
    const int gm = bm * 128 + tid;
    const int q0 = ids[2 * gm + 0];
    const int q1 = ids[2 * gm + 1];
    p0s[tid] = q0 < 0 ? 0 : q0;
    p1s[tid] = q1 < 0 ? 0 : q1;
    mks[tid] = padm[gm];
  }

  f32x4 acc[4][4];
#pragma unroll
  for (int i = 0; i < 4; ++i)
#pragma unroll
    for (int j = 0; j < 4; ++j) acc[i][j] = f32x4{0.f, 0.f, 0.f, 0.f};

  // ---- B staging geometry (gload_lds, pre-swizzled source) ----
  const int srow = l >> 2;
  const int sk   = ((l & 3) ^ ((l >> 3) & 3)) * 8;  // swizzled src k-chunk
  const int64_t bbase = (int64_t)(bn * 128) * K_PAD;

  // ---- A reg-staging geometry ----
  const int arow = tid >> 3;        // 0..31 (row within 32-row stripe)
  const int achk = tid & 7;         // 0..7 (4-float chunk)
  const int64_t arowbase = (int64_t)(bm * 128) * K_ORIG;
  f32x4 areg[4];

  // ---- Frag-read LDS element offsets (swizzle: g' = g ^ ((row>>1)&3)) ----
  int ra[4], rb[4];
#pragma unroll
  for (int mi = 0; mi < 4; ++mi) {
    const int rA = wm * 64 + mi * 16 + (l & 15);
    ra[mi] = rA * 32 + (((l >> 4) ^ ((rA >> 1) & 3)) * 8);
    const int rB = wn * 64 + mi * 16 + (l & 15);
    rb[mi] = rB * 32 + (((l >> 4) ^ ((rB >> 1) & 3)) * 8);
  }

  auto stageB = [&](int kt, int buf) {
    const int k0 = kt * 32;
#pragma unroll
    for (int i = 0; i < 2; ++i) {
      const int r0 = (w * 2 + i) * 16;
      gload_lds16(Bt + bbase + (int64_t)(r0 + srow) * K_PAD + k0 + sk,
                  &Bsh[buf][r0 * 32]);
    }
  };

  auto loadA = [&](int kt) {
    const int k = kt * 32 + achk * 4;
    const bool v = (k < K_ORIG);  // 588 % 4 == 0: chunks fully in or out
    const f32x4 zero = {0.f, 0.f, 0.f, 0.f};
#pragma unroll
    for (int rb4 = 0; rb4 < 4; ++rb4) {
      const int row = rb4 * 32 + arow;
      areg[rb4] = v ? *(const f32x4*)(px + arowbase + (int64_t)row * K_ORIG + k)
                    : zero;
    }
  };

  auto writeA = [&](int buf) {
    const int g   = achk >> 1;
    const int sub = (achk & 1) * 4;
#pragma unroll
    for (int rb4 = 0; rb4 < 4; ++rb4) {
      const int row = rb4 * 32 + arow;
      const int off = row * 32 + ((g ^ ((row >> 1) & 3)) * 8) + sub;
      ushort4 o;
      o.x = f2bf(__builtin_fmaf(2.f, areg[rb4][0], -1.f));
      o.y = f2bf(__builtin_fmaf(2.f, areg[rb4][1], -1.f));
      o.z = f2bf(__builtin_fmaf(2.f, areg[rb4][2], -1.f));
      o.w = f2bf(__builtin_fmaf(2.f, areg[rb4][3], -1.f));
      *(ushort4*)&Ash[buf][off] = o;
    }
  };

  // ---- Prologue: fill buffer 0 ----
  loadA(0);
  stageB(0, 0);
  writeA(0);           // compiler waits vmcnt for areg before the cvt
  __syncthreads();     // drains B gload (vmcnt 0) + A ds_writes

  // ---- Main loop: 1 barrier per K-step, loads overlapped with MFMA ----
  for (int t = 0; t < KT_STEPS; ++t) {
    const int cur = t & 1;
    const bool more = (t + 1 < KT_STEPS);
    if (more) {
      stageB(t + 1, cur ^ 1);
      loadA(t + 1);
    }

    bf16x8 av[4], bv[4];
#pragma unroll
    for (int mi = 0; mi < 4; ++mi) av[mi] = *(const bf16x8*)&Ash[cur][ra[mi]];
#pragma unroll
    for (int ni = 0; ni < 4; ++ni) bv[ni] = *(const bf16x8*)&Bsh[cur][rb[ni]];
#pragma unroll
    for (int mi = 0; mi < 4; ++mi)
#pragma unroll
      for (int ni = 0; ni < 4; ++ni)
        acc[mi][ni] = __builtin_amdgcn_mfma_f32_16x16x32_bf16(
            av[mi], bv[ni], acc[mi][ni], 0, 0, 0);

    if (more) {
      writeA(cur ^ 1);   // safe: last read of Ash[cur^1] was before prev barrier
      __syncthreads();   // A writes visible; B(t+1) landed; reads of [cur] done
    }
  }

  // ---- Epilogue: C/D layout col = lane&15, row = (lane>>4)*4 + reg (m89) ----
  const int c  = l & 15;
  const int rg = (l >> 4) * 4;
  const float* T0 = ptab;
  const float* T1 = ptab + (int64_t)P_DIM * H_DIM;
  const int hcol0 = bn * 128 + wn * 64;

#pragma unroll
  for (int mi = 0; mi < 4; ++mi) {
#pragma unroll
    for (int j = 0; j < 4; ++j) {
      const int r = wm * 64 + mi * 16 + rg + j;
      const int64_t gm = (int64_t)bm * 128 + r;
      const bool pad = mks[r] != 0;
      const float* t0 = T0 + (int64_t)p0s[r] * H_DIM;
      const float* t1 = T1 + (int64_t)p1s[r] * H_DIM;
      float* orow = out + gm * H_DIM;
#pragma unroll
      for (int ni = 0; ni < 4; ++ni) {
        const int gh = hcol0 + ni * 16 + c;
        const float pe = pad ? 0.f : (t0[gh] + t1[gh]);
        orow[gh] = acc[mi][ni][j] + pe;
      }
    }
  }
}

extern "C" void kernel_launch(void* const* d_in, const int* in_sizes, int n_in,
                              void* d_out, int out_size, void* d_ws,
                              size_t ws_size, hipStream_t stream) {
  const float* px            = (const float*)d_in[0];
  const int* ids             = (const int*)d_in[1];
  const unsigned char* padm  = (const unsigned char*)d_in[2];
  const float* W             = (const float*)d_in[3];
  const float* pt            = (const float*)d_in[4];
  float* out                 = (float*)d_out;

  unsigned short* Wt = (unsigned short*)d_ws;   // 1.4 MB

  // 19 k-tiles * 36 h-tiles
  convert_w<<<19 * 36, 256, 0, stream>>>(W, Wt);
  // (65536/128) * (1152/128) = 512*9 = 4608 blocks
  gemm_fused<<<4608, 256, 0, stream>>>(px, Wt, ids, padm, pt, out);
}